// Round 2
// baseline (1533.316 us; speedup 1.0000x reference)
//
#include <hip/hip_runtime.h>
#include <math.h>

typedef unsigned int u32;
typedef unsigned long long u64;

#define NANCH 6402
#define NCLS 80
#define TOPK 200
#define MAXN 100
#define BCAP 384  // per-(batch,class) candidate bucket capacity (mean ~185, sd ~13 -> 15 sigma)

// ---------- helpers ----------
__device__ __forceinline__ u32 sortable_u32(float f) {
  u32 u = __float_as_uint(f);
  return u ^ ((u32)(((int)u) >> 31) | 0x80000000u);
}
__device__ __forceinline__ float unsortable_f(u32 u) {
  u32 f = (u & 0x80000000u) ? (u ^ 0x80000000u) : ~u;
  return __uint_as_float(f);
}

// descending bitonic sort of P (power of 2) u64 keys in LDS, 256 threads
__device__ void bitonic_desc(u64* keys, int P, int tid) {
  for (int k = 2; k <= P; k <<= 1) {
    for (int j = k >> 1; j > 0; j >>= 1) {
      for (int i = tid; i < P; i += 256) {
        int l = i ^ j;
        if (l > i) {
          u64 a = keys[i], b = keys[l];
          bool desc = ((i & k) == 0);
          if (desc ? (a < b) : (a > b)) { keys[i] = b; keys[l] = a; }
        }
      }
      __syncthreads();
    }
  }
}

// ---------- kernel 1: softmax stats + candidate emission + bbox decode ----------
template<int W, int HW, int BS, int OFF>
__device__ void prep_level(int t, const float* __restrict__ cls,
                           const float* __restrict__ box,
                           float4* __restrict__ bbox,
                           u64* __restrict__ bkeys, int* __restrict__ bcnt) {
  if (t >= 64 * 3 * HW) return;
  int b = t / (3 * HW);
  int rem = t - b * 3 * HW;
  int a = rem / HW;
  int hw = rem - a * HW;

  const float* cbase = cls + ((size_t)b * 243 + (size_t)a * 81) * HW + hw;
  float m = cbase[0];
#pragma unroll 4
  for (int c = 1; c < 81; ++c) m = fmaxf(m, cbase[(size_t)c * HW]);
  double den = 0.0;
#pragma unroll 4
  for (int c = 0; c < 81; ++c) den += (double)expf(cbase[(size_t)c * HW] - m);
  float den_f = (float)den;

  int n = OFF + hw * 3 + a;  // anchor-major flat index (matches reference flatten)

  // candidate emission: s > 0.05 <=> x > m + log(0.05*den); 1e-3 logit margin
  // covers all f32 rounding; exact f32 gate re-applied in k_nms.
  float thr = m + logf(0.05f * den_f) - 1e-3f;
  for (int c = 0; c < 80; ++c) {  // class 80 is background (dropped column)
    float x = cbase[(size_t)c * HW];
    if (x > thr) {
      float s = expf(x - m) / den_f;  // bit-identical to round-0 score
      int bi = b * NCLS + c;
      int pos = atomicAdd(&bcnt[bi], 1);
      if (pos < BCAP)
        bkeys[(size_t)bi * BCAP + pos] =
            ((u64)__float_as_uint(s) << 32) | (u32)(~(u32)n);
    }
  }

  // bbox decode (anchors in fp64, matching numpy reference)
  const float* bb = box + ((size_t)b * 12 + (size_t)a * 4) * HW + hw;
  float d0 = bb[0] * 0.1f;
  float d1 = bb[HW] * 0.1f;
  float d2 = bb[2 * HW] * 0.2f;
  float d3 = bb[3 * HW] * 0.2f;
  const float MR = 4.135166556742356f;  // |log(0.016)|
  d2 = fminf(fmaxf(d2, -MR), MR);
  d3 = fminf(fmaxf(d3, -MR), MR);

  int x = hw % W, y = hw / W;
  double r = (a == 0) ? 0.5 : ((a == 1) ? 1.0 : 2.0);
  double hr = sqrt(r), wr = 1.0 / hr;
  double wsd = ((double)BS * wr) * 3.0;
  double hsd = ((double)BS * hr) * 3.0;
  double cc = (double)BS * 0.5;
  double sx = (double)(x * BS), sy = (double)(y * BS);
  float ax0 = (float)((cc - 0.5 * wsd) + sx);
  float ay0 = (float)((cc - 0.5 * hsd) + sy);
  float ax1 = (float)((cc + 0.5 * wsd) + sx);
  float ay1 = (float)((cc + 0.5 * hsd) + sy);

  float px = (ax0 + ax1) * 0.5f, py = (ay0 + ay1) * 0.5f;
  float pw = ax1 - ax0, ph = ay1 - ay0;
  float gx = px + pw * d0, gy = py + ph * d1;
  float gw = pw * expf(d2), gh = ph * expf(d3);
  float x0 = fminf(fmaxf(gx - 0.5f * gw, 0.f), 320.f);
  float y0 = fminf(fmaxf(gy - 0.5f * gh, 0.f), 320.f);
  float x1 = fminf(fmaxf(gx + 0.5f * gw, 0.f), 320.f);
  float y1 = fminf(fmaxf(gy + 0.5f * gh, 0.f), 320.f);
  bbox[(size_t)b * NANCH + n] = make_float4(x0, y0, x1, y1);
}

__global__ __launch_bounds__(256) void k_prep(
    const float* c0, const float* c1, const float* c2, const float* c3, const float* c4,
    const float* b0, const float* b1, const float* b2, const float* b3, const float* b4,
    float4* bbox, u64* bkeys, int* bcnt) {
  int bid = blockIdx.x, tid = threadIdx.x;
  if (bid < 1200)      prep_level<40, 1600, 8, 0>(bid * 256 + tid, c0, b0, bbox, bkeys, bcnt);
  else if (bid < 1500) prep_level<20, 400, 16, 4800>((bid - 1200) * 256 + tid, c1, b1, bbox, bkeys, bcnt);
  else if (bid < 1575) prep_level<10, 100, 32, 6000>((bid - 1500) * 256 + tid, c2, b2, bbox, bkeys, bcnt);
  else if (bid < 1594) prep_level<5, 25, 64, 6300>((bid - 1575) * 256 + tid, c3, b3, bbox, bkeys, bcnt);
  else                 prep_level<3, 9, 128, 6375>((bid - 1594) * 256 + tid, c4, b4, bbox, bkeys, bcnt);
}

// ---------- kernel 2: per-(batch,class) sort + Fast NMS ----------
__global__ __launch_bounds__(256) void k_nms(
    const u64* __restrict__ bkeys, const int* __restrict__ bcnt,
    const float4* __restrict__ bbox,
    float* __restrict__ val, int* __restrict__ anc) {
  __shared__ u64 keys[512];
  __shared__ float4 boxes[TOPK];
  __shared__ int supp[TOPK];
  int tid = threadIdx.x, bid = blockIdx.x;
  int b = bid / NCLS;
  int cnt = bcnt[bid];
  if (cnt > BCAP) cnt = BCAP;
  const u64* src = bkeys + (size_t)bid * BCAP;
  for (int i = tid; i < 512; i += 256) keys[i] = (i < cnt) ? src[i] : 0ULL;
  if (tid < TOPK) supp[tid] = 0;
  __syncthreads();
  bitonic_desc(keys, (cnt <= 256) ? 256 : 512, tid);

  int K2 = min(cnt, TOPK);
  for (int k = tid; k < K2; k += 256) {
    u32 n = ~((u32)keys[k]);
    boxes[k] = bbox[(size_t)b * NANCH + n];
  }
  __syncthreads();

  // Fast NMS, column-paired load balance: thread t -> col t; plus col K2-1-t if >= 128
  for (int pass = 0; pass < 2; ++pass) {
    int j = (pass == 0) ? tid : (K2 - 1 - tid);
    if (pass == 0) { if (j >= K2) continue; }
    else           { if (j < 128 || j >= K2) continue; }
    float4 bj = boxes[j];
    float aj = (bj.z - bj.x) * (bj.w - bj.y);
    int sflag = 0;
    for (int i = 0; i < j; ++i) {
      float4 bi = boxes[i];
      float wx = fmaxf(fminf(bi.z, bj.z) - fmaxf(bi.x, bj.x), 0.f);
      float wy = fmaxf(fminf(bi.w, bj.w) - fmaxf(bi.y, bj.y), 0.f);
      float ov = wx * wy;
      float ai = (bi.z - bi.x) * (bi.w - bi.y);
      float un = fmaxf(ai + aj - ov, 1e-6f);
      bool sp;
      if (ov > un * 0.505f) sp = true;                  // certainly iou > 0.5
      else if (ov > un * 0.495f) sp = (ov / un > 0.5f); // exact IEEE division in the band
      else sp = false;
      if (sp) { sflag = 1; break; }
    }
    if (sflag) supp[j] = 1;
  }
  __syncthreads();

  float* valp = val + (size_t)bid * TOPK;
  int* ancp = anc + (size_t)bid * TOPK;
  if (tid < TOPK) {
    if (tid < K2) {
      float s = __uint_as_float((u32)(keys[tid] >> 32));
      u32 n = ~((u32)keys[tid]);
      bool keep = (!supp[tid]) && (s > 0.05f);  // exact f32 gate
      valp[tid] = keep ? s : -1.0f;
      ancp[tid] = (int)n;
    } else {
      valp[tid] = -1.0f;
      ancp[tid] = -1;
    }
  }
}

// ---------- kernel 3: per-batch top-100 (radix select) + gather ----------
__global__ __launch_bounds__(256) void k_top(
    const float* __restrict__ val, const int* __restrict__ anc,
    const float4* __restrict__ bbox,
    const float* f0, const float* f1, const float* f2, const float* f3, const float* f4,
    float* __restrict__ out, float* __restrict__ csel) {
  int b = blockIdx.x, tid = threadIdx.x;
  const float* vp = val + (size_t)b * 16000;

  u32 uloc[63];
#pragma unroll
  for (int k = 0; k < 63; ++k) {
    int i = tid + (k << 8);
    uloc[k] = (i < 16000) ? sortable_u32(vp[i]) : 0u;
  }

  // 4-round radix select for the 100th-largest sortable value
  __shared__ int hist[256];
  __shared__ int sh_sel, sh_need;
  u32 prefix = 0;
  int need = MAXN;
  for (int round = 0; round < 4; ++round) {
    int shift = 24 - (round << 3);
    hist[tid] = 0;
    __syncthreads();
#pragma unroll
    for (int k = 0; k < 63; ++k) {
      int i = tid + (k << 8);
      u32 u = uloc[k];
      bool ok = (i < 16000);
      if (round > 0) ok = ok && ((u >> (shift + 8)) == prefix);
      if (ok) atomicAdd(&hist[(u >> shift) & 255], 1);
    }
    __syncthreads();
    if (tid < 64) {
      int h0 = hist[tid * 4], h1 = hist[tid * 4 + 1];
      int h2 = hist[tid * 4 + 2], h3 = hist[tid * 4 + 3];
      int loc = h0 + h1 + h2 + h3;
      int suf = loc;
#pragma unroll
      for (int off = 1; off < 64; off <<= 1) {
        int v = __shfl_down(suf, off);
        if (tid + off < 64) suf += v;
      }
      int cg0 = suf, cg1 = suf - h0, cg2 = cg1 - h1, cg3 = cg2 - h2, cg4 = cg3 - h3;
      if (cg0 >= need && cg1 < need) { sh_sel = tid * 4;     sh_need = need - cg1; }
      if (cg1 >= need && cg2 < need) { sh_sel = tid * 4 + 1; sh_need = need - cg2; }
      if (cg2 >= need && cg3 < need) { sh_sel = tid * 4 + 2; sh_need = need - cg3; }
      if (cg3 >= need && cg4 < need) { sh_sel = tid * 4 + 3; sh_need = need - cg4; }
    }
    __syncthreads();
    prefix = (prefix << 8) | (u32)sh_sel;
    need = sh_need;
  }
  u32 V = prefix;  // sortable bits of the 100th largest

  __shared__ u64 ckey[512];
  __shared__ int cnt2;
  if (tid == 0) cnt2 = 0;
  __syncthreads();
#pragma unroll
  for (int k = 0; k < 63; ++k) {
    int i = tid + (k << 8);
    if (i < 16000 && uloc[k] >= V) {
      int p = atomicAdd(&cnt2, 1);
      if (p < 512) ckey[p] = ((u64)uloc[k] << 32) | (u32)(~(u32)i);
    }
  }
  __syncthreads();
  int m2 = min(cnt2, 512);
  for (int i = m2 + tid; i < 512; i += 256) ckey[i] = 0ULL;
  __syncthreads();
  bitonic_desc(ckey, 512, tid);

  __shared__ int selanc[MAXN];
  if (tid < MAXN) {
    u64 kk = ckey[tid];
    u32 u = (u32)(kk >> 32);
    float v = unsortable_f(u);
    u32 flat = ~(u32)(kk & 0xFFFFFFFFULL);
    int ccls = (int)(flat / 200u);
    int an = anc[(size_t)b * 16000 + flat];
    float4 bx = (an >= 0) ? bbox[(size_t)b * NANCH + an] : make_float4(0.f, 0.f, 0.f, 0.f);
    float* dout = out + (size_t)b * 500 + (size_t)tid * 5;
    dout[0] = bx.x; dout[1] = bx.y; dout[2] = bx.z; dout[3] = bx.w; dout[4] = v;
    out[32000 + (size_t)b * 100 + tid] = (float)ccls;
    selanc[tid] = an;
  }
  __syncthreads();

  float* cp = csel + (size_t)b * 3200;
  for (int idx = tid; idx < 3200; idx += 256) {
    int kk = idx >> 5, q = idx & 31;
    int an = selanc[kk];
    float cv = 0.f;
    if (an >= 0) {
      if (an < 4800)      { int rel = an;        int hw = rel / 3, a = rel % 3; cv = f0[((size_t)b * 96 + (size_t)(a * 32 + q)) * 1600 + hw]; }
      else if (an < 6000) { int rel = an - 4800; int hw = rel / 3, a = rel % 3; cv = f1[((size_t)b * 96 + (size_t)(a * 32 + q)) * 400 + hw]; }
      else if (an < 6300) { int rel = an - 6000; int hw = rel / 3, a = rel % 3; cv = f2[((size_t)b * 96 + (size_t)(a * 32 + q)) * 100 + hw]; }
      else if (an < 6375) { int rel = an - 6300; int hw = rel / 3, a = rel % 3; cv = f3[((size_t)b * 96 + (size_t)(a * 32 + q)) * 25 + hw]; }
      else                { int rel = an - 6375; int hw = rel / 3, a = rel % 3; cv = f4[((size_t)b * 96 + (size_t)(a * 32 + q)) * 9 + hw]; }
    }
    cp[idx] = cv;
  }
}

// ---------- kernel 4: masks = sigmoid(proto @ cselT), LDS-staged coalesced stores ----------
__global__ __launch_bounds__(256) void k_mask(const float* __restrict__ proto,
                                              const float* __restrict__ csel,
                                              float* __restrict__ outm) {
  // lds layout: S = [0,3600) stride 36; Pt = [3600, 7824) stride 33.
  // After compute, lds[0,6400) is reused as the store-staging buffer.
  __shared__ __align__(16) float lds[7824];
  float* S = lds;
  float* Pt = lds + 3600;
  int bid = blockIdx.x;
  int b = bid / 50, tile = bid - b * 50;
  int tid = threadIdx.x;

  const float* cs = csel + (size_t)b * 3200;
  for (int i = tid; i < 3200; i += 256) {
    int n = i >> 5, j = i & 31;
    S[n * 36 + j] = cs[i];
  }
  const float* pp = proto + (size_t)b * 204800 + (size_t)tile * 4096;
  for (int i = tid; i < 4096; i += 256) {
    int r2 = i >> 5, j = i & 31;
    Pt[r2 * 33 + j] = pp[i];
  }
  __syncthreads();

  int q = tid & 3, r = tid >> 2;  // rows r and r+64; q picks 25-col chunk
  float p0[32], p1[32];
#pragma unroll
  for (int j = 0; j < 32; ++j) { p0[j] = Pt[r * 33 + j]; p1[j] = Pt[(r + 64) * 33 + j]; }

  float a0[25], a1[25];
#pragma unroll
  for (int i = 0; i < 25; ++i) {
    int n = q * 25 + i;
    const float4* sp = (const float4*)&S[n * 36];
    float x0 = 0.f, x1 = 0.f;
#pragma unroll
    for (int jc = 0; jc < 8; ++jc) {
      float4 sv = sp[jc];
      x0 += p0[jc * 4 + 0] * sv.x; x1 += p1[jc * 4 + 0] * sv.x;
      x0 += p0[jc * 4 + 1] * sv.y; x1 += p1[jc * 4 + 1] * sv.y;
      x0 += p0[jc * 4 + 2] * sv.z; x1 += p1[jc * 4 + 2] * sv.z;
      x0 += p0[jc * 4 + 3] * sv.w; x1 += p1[jc * 4 + 3] * sv.w;
    }
    a0[i] = x0; a1[i] = x1;
  }
  __syncthreads();

  float* g0 = outm + (size_t)b * 640000 + (size_t)tile * 12800;
#pragma unroll
  for (int i = 0; i < 25; ++i) lds[r * 100 + q * 25 + i] = 1.f / (1.f + expf(-a0[i]));
  __syncthreads();
  for (int k = tid; k < 1600; k += 256) ((float4*)g0)[k] = ((const float4*)lds)[k];
  __syncthreads();
#pragma unroll
  for (int i = 0; i < 25; ++i) lds[r * 100 + q * 25 + i] = 1.f / (1.f + expf(-a1[i]));
  __syncthreads();
  for (int k = tid; k < 1600; k += 256) ((float4*)(g0 + 6400))[k] = ((const float4*)lds)[k];
}

// ---------- launch ----------
extern "C" void kernel_launch(void* const* d_in, const int* in_sizes, int n_in,
                              void* d_out, int out_size, void* d_ws, size_t ws_size,
                              hipStream_t stream) {
  const float* c0 = (const float*)d_in[0];
  const float* c1 = (const float*)d_in[1];
  const float* c2 = (const float*)d_in[2];
  const float* c3 = (const float*)d_in[3];
  const float* c4 = (const float*)d_in[4];
  const float* b0 = (const float*)d_in[5];
  const float* b1 = (const float*)d_in[6];
  const float* b2 = (const float*)d_in[7];
  const float* b3 = (const float*)d_in[8];
  const float* b4 = (const float*)d_in[9];
  const float* f0 = (const float*)d_in[10];
  const float* f1 = (const float*)d_in[11];
  const float* f2 = (const float*)d_in[12];
  const float* f3 = (const float*)d_in[13];
  const float* f4 = (const float*)d_in[14];
  const float* proto = (const float*)d_in[15];
  float* out = (float*)d_out;

  float* w = (float*)d_ws;
  // workspace layout (float units):
  // bbox : [0,         1638912)           64*6402*4
  // val  : [1638912,   2662912)           64*16000
  // anc  : [2662912,   3686912)           64*16000 (int)
  // csel : [3686912,   3891712)           64*100*32
  // bcnt : [3891712,   3896832)           5120 (int)
  // bkeys: [3896832,   7828992)           5120*384 u64 (byte offset 15587328, 8B-aligned)
  float4* bbox = (float4*)w;
  float* val = w + 1638912;
  int* anc = (int*)(w + 2662912);
  float* csel = w + 3686912;
  int* bcnt = (int*)(w + 3891712);
  u64* bkeys = (u64*)(w + 3896832);

  hipMemsetAsync(bcnt, 0, 5120 * sizeof(int), stream);
  k_prep<<<1601, 256, 0, stream>>>(c0, c1, c2, c3, c4, b0, b1, b2, b3, b4, bbox, bkeys, bcnt);
  k_nms<<<64 * NCLS, 256, 0, stream>>>(bkeys, bcnt, bbox, val, anc);
  k_top<<<64, 256, 0, stream>>>(val, anc, bbox, f0, f1, f2, f3, f4, out, csel);
  k_mask<<<3200, 256, 0, stream>>>(proto, csel, out + 38400);
}